// Round 1
// baseline (7525.533 us; speedup 1.0000x reference)
//
#include <hip/hip_runtime.h>
#include <cstdint>
#include <cstddef>

// ---------------------------------------------------------------------------
// CNN (conv1+pool, conv2+pool)  ->  seq [256][256][32]
// NTM scan: 64 persistent blocks x 1024 threads, 4 batch elements per block.
// All recurrent state (h, c, M, w_prev, reads) per-block in LDS/registers;
// weights streamed from L2 each step. No grid syncs (batch-independent).
// ---------------------------------------------------------------------------

#define MW    20      // memory width
#define NLOC  128     // memory locations
#define KTOT  308     // 32 (xt) + 20 (reads) + 256 (h)
#define ZC    1024    // 4*UNITS
#define PC    92      // NH*PPH + 2*W*WH = 52 + 40
#define CLIPV 20.0f

__device__ __forceinline__ float sigmoidf_(float x) { return 1.0f / (1.0f + expf(-x)); }
__device__ __forceinline__ float softplusf_(float x) { return log1pf(expf(x)); }

// Build combined W [308][1024]: rows 0..51 = lstm_wx, rows 52..307 = lstm_wh
__global__ __launch_bounds__(256) void prep_W(const float* __restrict__ wx,
                                              const float* __restrict__ wh,
                                              float* __restrict__ W) {
    int idx = blockIdx.x * 256 + threadIdx.x;   // 308*1024 = 315392
    if (idx >= KTOT * ZC) return;
    int k = idx >> 10, j = idx & 1023;
    W[idx] = (k < 52) ? wx[k * ZC + j] : wh[(k - 52) * ZC + j];
}

// conv1 3x3 (1->16) SAME + relu + maxpool2 : in [256][64][64] -> p1 [256][32][32][16]
__global__ __launch_bounds__(256) void conv1_pool(const float* __restrict__ in,
                                                  const float* __restrict__ w,
                                                  const float* __restrict__ bias,
                                                  float* __restrict__ out) {
    int idx = blockIdx.x * 256 + threadIdx.x;   // 256*32*32*16
    if (idx >= 256 * 32 * 32 * 16) return;
    int c = idx & 15, x = (idx >> 4) & 31, y = (idx >> 9) & 31, b = idx >> 14;
    const float* inb = in + (size_t)b * 4096;
    float bv = bias[c];
    float mx = 0.0f;  // relu outputs are >= 0
    #pragma unroll
    for (int dy = 0; dy < 2; ++dy)
    #pragma unroll
    for (int dx = 0; dx < 2; ++dx) {
        int oy = 2 * y + dy, ox = 2 * x + dx;
        float s = bv;
        #pragma unroll
        for (int ky = 0; ky < 3; ++ky) {
            int iy = oy + ky - 1;
            if (iy < 0 || iy > 63) continue;
            #pragma unroll
            for (int kx = 0; kx < 3; ++kx) {
                int ix = ox + kx - 1;
                if (ix < 0 || ix > 63) continue;
                s = fmaf(inb[iy * 64 + ix], w[(ky * 3 + kx) * 16 + c], s);
            }
        }
        mx = fmaxf(mx, fmaxf(s, 0.0f));
    }
    out[idx] = mx;
}

// conv2 3x3 (16->32) SAME + relu + maxpool2 : p1 [256][32][32][16] -> seq [256][256][32]
__global__ __launch_bounds__(256) void conv2_pool(const float* __restrict__ p1,
                                                  const float* __restrict__ w,
                                                  const float* __restrict__ bias,
                                                  float* __restrict__ seq) {
    int idx = blockIdx.x * 256 + threadIdx.x;   // 256*16*16*32
    if (idx >= 256 * 16 * 16 * 32) return;
    int c = idx & 31, x = (idx >> 5) & 15, y = (idx >> 9) & 15, b = idx >> 13;
    const float* pb = p1 + (size_t)b * (32 * 32 * 16);
    float bv = bias[c];
    float mx = 0.0f;
    #pragma unroll
    for (int dy = 0; dy < 2; ++dy)
    #pragma unroll
    for (int dx = 0; dx < 2; ++dx) {
        int oy = 2 * y + dy, ox = 2 * x + dx;
        float s = bv;
        for (int ky = 0; ky < 3; ++ky) {
            int iy = oy + ky - 1;
            if (iy < 0 || iy > 31) continue;
            for (int kx = 0; kx < 3; ++kx) {
                int ix = ox + kx - 1;
                if (ix < 0 || ix > 31) continue;
                const float* pin = pb + (iy * 32 + ix) * 16;
                const float* pw  = w + (ky * 3 + kx) * 16 * 32 + c;
                #pragma unroll
                for (int ci2 = 0; ci2 < 16; ++ci2)
                    s = fmaf(pin[ci2], pw[ci2 * 32], s);
            }
        }
        mx = fmaxf(mx, fmaxf(s, 0.0f));
    }
    seq[idx] = mx;   // [b][y][x][c] == [b][t=y*16+x][c]
}

// ---------------------------------------------------------------------------
// Persistent NTM scan. 64 blocks, 4 batch/block, 1024 threads (16 waves).
// ---------------------------------------------------------------------------
__global__ __launch_bounds__(1024) void ntm_scan(
    const float* __restrict__ seq,   // [256][256][32]
    const float* __restrict__ W,     // [308][1024]
    const float* __restrict__ lb,    // [1024]
    const float* __restrict__ hw,    // [256][92]
    const float* __restrict__ hb,    // [92]
    const float* __restrict__ ow,    // [276][8]
    const float* __restrict__ ob,    // [8]
    float* __restrict__ out8)        // [256][8]
{
    __shared__ float zpart[4][4][ZC];          // [kq][b][col] 64KB
    __shared__ float ci[4][KTOT];              // [b][k]: 0..31 xt, 32..51 reads, 52..307 h
    __shared__ float Msh[4][NLOC][MW + 1];     // pad 21 -> conflict-free strided reads
    __shared__ float wprev[4][2][NLOC];
    __shared__ float wgs[4][2][NLOC];
    __shared__ float ps[4][PC];
    __shared__ float pp[2][4][PC];
    __shared__ float kv[4][2][MW];
    __shared__ float ev[4][MW];
    __shared__ float av[4][MW];
    __shared__ float hpar[4][2][8];            // beta,g,gamma,s0,s1,s2,kdenom
    __shared__ float redA[8][2], redB[8][2], redC[8][2];
    __shared__ float rdp[8][4][MW];

    const int t = threadIdx.x;
    const int bs0 = blockIdx.x * 4;

    // ---- init state ----
    for (int i = t; i < 4 * KTOT; i += 1024) {
        int b = i / KTOT, k = i - b * KTOT;
        float v;
        if (k < 32)      v = seq[(size_t)(bs0 + b) * 8192 + k];   // xt at t=0
        else if (k < 52) v = 1e-6f;                               // reads init
        else             v = 0.0f;                                // h init
        ci[b][k] = v;
    }
    for (int i = t; i < 4 * NLOC * MW; i += 1024) {
        int b = i / (NLOC * MW), r = i - b * (NLOC * MW);
        Msh[b][r / MW][r - (r / MW) * MW] = 1e-6f;
    }
    for (int i = t; i < 4 * 2 * NLOC; i += 1024) {
        int b = i >> 8, r = i & 255;
        wprev[b][r >> 7][r & 127] = 1.0f / 128.0f;
    }
    float c_reg = 0.0f;   // cell state: thread t owns (b=t>>8, u=t&255)
    __syncthreads();

    const int kq = t >> 8;          // K-quarter 0..3
    const int jc = t & 255;         // column group (4 cols each)
    const int j4 = jc << 2;
    const int k0 = kq * 80;                      // 0,80,160,240
    const int klen = (kq == 3) ? 68 : 80;        // 240+68 = 308

    for (int step = 0; step < 256; ++step) {
        // ---- P1: z partial GEMM: zpart[kq][b][j4..j4+3] ----
        {
            float a0=0,a1=0,a2=0,a3=0, b0=0,b1=0,b2=0,b3=0;
            float e0=0,e1=0,e2=0,e3=0, f0=0,f1=0,f2=0,f3=0;
            const float* Wp = W + (size_t)k0 * ZC + j4;
            for (int kb = 0; kb < klen; kb += 4) {
                int k = k0 + kb;
                float cA[4], cB[4], cC[4], cD[4];
                *reinterpret_cast<float4*>(cA) = *reinterpret_cast<const float4*>(&ci[0][k]);
                *reinterpret_cast<float4*>(cB) = *reinterpret_cast<const float4*>(&ci[1][k]);
                *reinterpret_cast<float4*>(cC) = *reinterpret_cast<const float4*>(&ci[2][k]);
                *reinterpret_cast<float4*>(cD) = *reinterpret_cast<const float4*>(&ci[3][k]);
                #pragma unroll
                for (int q = 0; q < 4; ++q) {
                    float4 wv = *reinterpret_cast<const float4*>(Wp + (size_t)q * ZC);
                    a0=fmaf(cA[q],wv.x,a0); a1=fmaf(cA[q],wv.y,a1); a2=fmaf(cA[q],wv.z,a2); a3=fmaf(cA[q],wv.w,a3);
                    b0=fmaf(cB[q],wv.x,b0); b1=fmaf(cB[q],wv.y,b1); b2=fmaf(cB[q],wv.z,b2); b3=fmaf(cB[q],wv.w,b3);
                    e0=fmaf(cC[q],wv.x,e0); e1=fmaf(cC[q],wv.y,e1); e2=fmaf(cC[q],wv.z,e2); e3=fmaf(cC[q],wv.w,e3);
                    f0=fmaf(cD[q],wv.x,f0); f1=fmaf(cD[q],wv.y,f1); f2=fmaf(cD[q],wv.z,f2); f3=fmaf(cD[q],wv.w,f3);
                }
                Wp += (size_t)4 * ZC;
            }
            *reinterpret_cast<float4*>(&zpart[kq][0][j4]) = make_float4(a0,a1,a2,a3);
            *reinterpret_cast<float4*>(&zpart[kq][1][j4]) = make_float4(b0,b1,b2,b3);
            *reinterpret_cast<float4*>(&zpart[kq][2][j4]) = make_float4(e0,e1,e2,e3);
            *reinterpret_cast<float4*>(&zpart[kq][3][j4]) = make_float4(f0,f1,f2,f3);
        }
        __syncthreads();

        // ---- P2: LSTM cell/hidden update ----
        {
            int b = t >> 8, u = t & 255;
            float zi = lb[u]       + zpart[0][b][u]       + zpart[1][b][u]       + zpart[2][b][u]       + zpart[3][b][u];
            float zf = lb[256 + u] + zpart[0][b][256 + u] + zpart[1][b][256 + u] + zpart[2][b][256 + u] + zpart[3][b][256 + u];
            float zg = lb[512 + u] + zpart[0][b][512 + u] + zpart[1][b][512 + u] + zpart[2][b][512 + u] + zpart[3][b][512 + u];
            float zo = lb[768 + u] + zpart[0][b][768 + u] + zpart[1][b][768 + u] + zpart[2][b][768 + u] + zpart[3][b][768 + u];
            float cg = sigmoidf_(zf) * c_reg + sigmoidf_(zi) * tanhf(zg);
            c_reg = cg;
            ci[b][52 + u] = sigmoidf_(zo) * tanhf(cg);
        }
        __syncthreads();

        // ---- P3: head params p = clip(h @ head_w + head_b) (2-way K split) ----
        if (t < 736) {
            int uq = t / 368, r = t - uq * 368;
            int b = r / PC, col = r - b * PC;
            float s = 0.0f;
            const float* hwp = hw + col;
            int u0 = uq * 128;
            for (int u = u0; u < u0 + 128; ++u)
                s = fmaf(ci[b][52 + u], hwp[u * PC], s);
            pp[uq][b][col] = s;
        }
        __syncthreads();
        if (t < 368) {
            int b = t / PC, col = t - b * PC;
            float s = pp[0][b][col] + pp[1][b][col] + hb[col];
            ps[b][col] = fminf(fmaxf(s, -CLIPV), CLIPV);
        }
        __syncthreads();

        // ---- P4a: per-head vectors and scalars ----
        if (t < 160) {
            int b = t / 40, r = t - b * 40, hh = r / 20, wi = r - hh * 20;
            kv[b][hh][wi] = tanhf(ps[b][hh * 26 + wi]);
        } else if (t >= 512 && t < 672) {
            int r = t - 512, b = r / 40, q = r - b * 40;
            if (q < 20) ev[b][q] = sigmoidf_(ps[b][52 + q]);
            else        av[b][q - 20] = tanhf(ps[b][72 + (q - 20)]);
        }
        __syncthreads();
        if (t < 8) {
            int b = t >> 1, hh = t & 1;
            const float* pb = &ps[b][hh * 26];
            float beta = softplusf_(pb[20]);
            float g    = sigmoidf_(pb[21]);
            float s0 = pb[22], s1 = pb[23], s2 = pb[24];
            float m = fmaxf(s0, fmaxf(s1, s2));
            float q0 = expf(s0 - m), q1 = expf(s1 - m), q2 = expf(s2 - m);
            float inv = 1.0f / (q0 + q1 + q2);
            float gamma = softplusf_(pb[25]) + 1.0f;
            float kn2 = 0.0f;
            #pragma unroll
            for (int wi = 0; wi < MW; ++wi) { float kk = kv[b][hh][wi]; kn2 = fmaf(kk, kk, kn2); }
            hpar[b][hh][0] = beta; hpar[b][hh][1] = g; hpar[b][hh][2] = gamma;
            hpar[b][hh][3] = q0 * inv; hpar[b][hh][4] = q1 * inv; hpar[b][hh][5] = q2 * inv;
            hpar[b][hh][6] = sqrtf(kn2) + 1e-8f;
        }
        __syncthreads();

        // ---- P4b: addressing. t = (b<<8)|(hh<<7)|n ----
        {
            int b = t >> 8, hh = (t >> 7) & 1, n = t & 127;
            int gid = t >> 7, wv_id = (t >> 6) & 1;
            float dot = 0.0f, m2 = 0.0f;
            #pragma unroll
            for (int wi = 0; wi < MW; ++wi) {
                float mv = Msh[b][n][wi];
                dot = fmaf(kv[b][hh][wi], mv, dot);
                m2  = fmaf(mv, mv, m2);
            }
            float x = hpar[b][hh][0] * (dot / ((sqrtf(m2) + 1e-8f) * hpar[b][hh][6]));
            float mx = x;
            #pragma unroll
            for (int o = 1; o < 64; o <<= 1) mx = fmaxf(mx, __shfl_xor(mx, o, 64));
            if ((t & 63) == 0) redA[gid][wv_id] = mx;
            __syncthreads();
            mx = fmaxf(redA[gid][0], redA[gid][1]);
            float ex = expf(x - mx);
            float sm = ex;
            #pragma unroll
            for (int o = 1; o < 64; o <<= 1) sm += __shfl_xor(sm, o, 64);
            if ((t & 63) == 0) redB[gid][wv_id] = sm;
            __syncthreads();
            float wc = ex / (redB[gid][0] + redB[gid][1]);
            float g = hpar[b][hh][1];
            float wg = g * wc + (1.0f - g) * wprev[b][hh][n];
            wgs[b][hh][n] = wg;
            __syncthreads();
            float wt = hpar[b][hh][3] * wgs[b][hh][(n + 1) & 127]
                     + hpar[b][hh][4] * wg
                     + hpar[b][hh][5] * wgs[b][hh][(n - 1) & 127];
            float wp = expf(hpar[b][hh][2] * logf(wt + 1e-8f));
            float ss = wp;
            #pragma unroll
            for (int o = 1; o < 64; o <<= 1) ss += __shfl_xor(ss, o, 64);
            if ((t & 63) == 0) redC[gid][wv_id] = ss;
            __syncthreads();
            wprev[b][hh][n] = wp / (redC[gid][0] + redC[gid][1]);
        }
        __syncthreads();

        // ---- P5: reads = w_read @ M (old M), 8-way n-chunks ----
        if (t < 640) {
            int nc = t / 80, r = t - nc * 80, b = r / 20, wi = r - b * 20;
            float s = 0.0f;
            int n0 = nc * 16;
            #pragma unroll
            for (int n = n0; n < n0 + 16; ++n)
                s = fmaf(wprev[b][0][n], Msh[b][n][wi], s);
            rdp[nc][b][wi] = s;
        }
        __syncthreads();
        if (t < 80) {
            int b = t / 20, wi = t - b * 20;
            float s = 0.0f;
            #pragma unroll
            for (int nc = 0; nc < 8; ++nc) s += rdp[nc][b][wi];
            ci[b][32 + wi] = s;
        }
        // ---- P6: memory write (erase+add) with write head ----
        for (int i = t; i < 4 * NLOC * MW; i += 1024) {
            int b = i / 2560, r = i - b * 2560, n = r / 20, wi = r - n * 20;
            float wwn = wprev[b][1][n];
            Msh[b][n][wi] = Msh[b][n][wi] * (1.0f - wwn * ev[b][wi]) + wwn * av[b][wi];
        }
        // ---- load next xt ----
        if (step < 255 && t < 128) {
            int b = t >> 5, cc = t & 31;
            ci[b][cc] = seq[(size_t)(bs0 + b) * 8192 + (size_t)(step + 1) * 32 + cc];
        }
        __syncthreads();

        if (step == 255 && t < 32) {
            int b = t >> 3, o = t & 7;
            float s = ob[o];
            for (int u = 0; u < 256; ++u) s = fmaf(ci[b][52 + u], ow[u * 8 + o], s);
            #pragma unroll
            for (int wi = 0; wi < MW; ++wi) s = fmaf(ci[b][32 + wi], ow[(256 + wi) * 8 + o], s);
            s = fminf(fmaxf(s, -CLIPV), CLIPV);
            out8[(bs0 + b) * 8 + o] = s;
        }
    }
}

// final dense [256,8]@[8,2] + softmax
__global__ __launch_bounds__(256) void final_dense(const float* __restrict__ out8,
                                                   const float* __restrict__ dw,
                                                   const float* __restrict__ db,
                                                   float* __restrict__ out) {
    int b = blockIdx.x * 256 + threadIdx.x;
    if (b >= 256) return;
    float l0 = db[0], l1 = db[1];
    #pragma unroll
    for (int k = 0; k < 8; ++k) {
        float v = out8[b * 8 + k];
        l0 = fmaf(v, dw[k * 2 + 0], l0);
        l1 = fmaf(v, dw[k * 2 + 1], l1);
    }
    float m = fmaxf(l0, l1);
    float q0 = expf(l0 - m), q1 = expf(l1 - m);
    float inv = 1.0f / (q0 + q1);
    out[b * 2 + 0] = q0 * inv;
    out[b * 2 + 1] = q1 * inv;
}

extern "C" void kernel_launch(void* const* d_in, const int* in_sizes, int n_in,
                              void* d_out, int out_size, void* d_ws, size_t ws_size,
                              hipStream_t stream) {
    const float* inputs = (const float*)d_in[0];
    const float* c1w = (const float*)d_in[1];
    const float* c1b = (const float*)d_in[2];
    const float* c2w = (const float*)d_in[3];
    const float* c2b = (const float*)d_in[4];
    const float* lwx = (const float*)d_in[5];
    const float* lwh = (const float*)d_in[6];
    const float* lb  = (const float*)d_in[7];
    const float* hw  = (const float*)d_in[8];
    const float* hb  = (const float*)d_in[9];
    const float* ow  = (const float*)d_in[10];
    const float* ob  = (const float*)d_in[11];
    const float* dw  = (const float*)d_in[12];
    const float* db  = (const float*)d_in[13];
    float* out = (float*)d_out;

    float* ws   = (float*)d_ws;
    float* p1   = ws;                  // 256*32*32*16 = 4,194,304 floats
    float* seq  = ws + 4194304;        // 256*256*32   = 2,097,152 floats
    float* W    = ws + 6291456;        // 308*1024     =   315,392 floats
    float* out8 = ws + 6606848;        // 256*8        =     2,048 floats
    // total ~26.4 MB of workspace

    hipLaunchKernelGGL(prep_W,      dim3(1232),  dim3(256),  0, stream, lwx, lwh, W);
    hipLaunchKernelGGL(conv1_pool,  dim3(16384), dim3(256),  0, stream, inputs, c1w, c1b, p1);
    hipLaunchKernelGGL(conv2_pool,  dim3(8192),  dim3(256),  0, stream, p1, c2w, c2b, seq);
    hipLaunchKernelGGL(ntm_scan,    dim3(64),    dim3(1024), 0, stream, seq, W, lb, hw, hb, ow, ob, out8);
    hipLaunchKernelGGL(final_dense, dim3(1),     dim3(256),  0, stream, out8, dw, db, out);
}

// Round 2
// 3902.956 us; speedup vs baseline: 1.9282x; 1.9282x over previous
//
#include <hip/hip_runtime.h>
#include <hip/hip_fp16.h>
#include <cstdint>
#include <cstddef>

// ---------------------------------------------------------------------------
// CNN (conv1+pool, conv2+pool)  ->  seq [256][256][32]
// NTM scan: 128 persistent blocks x 1024 threads, 2 batch elements per block.
// LDS > 80KB forces 1 block/CU -> 128 distinct CUs.
// Weights packed fp16 (k-pairs) -> 640KB/step L2 stream per CU.
// ---------------------------------------------------------------------------

#define MW    20
#define NLOC  128
#define ZC    1024
#define PC    92
#define CLIPV 20.0f
#define KPAD  320            // K padded: 32 xt + 20 reads + 256 h = 308 -> 320
#define NPR   160            // KPAD/2 packed fp16 pairs

__device__ __forceinline__ float sigmoidf_(float x) { return 1.0f / (1.0f + expf(-x)); }
__device__ __forceinline__ float softplusf_(float x) { return log1pf(expf(x)); }

// Pack combined W [308][1024] (rows 0..51 wx, 52..307 wh) into half2 k-pairs.
__global__ __launch_bounds__(256) void prep_W2(const float* __restrict__ wx,
                                               const float* __restrict__ wh,
                                               __half2* __restrict__ W2) {
    int idx = blockIdx.x * 256 + threadIdx.x;   // NPR*1024
    if (idx >= NPR * ZC) return;
    int pr = idx >> 10, j = idx & 1023;
    int k0 = 2 * pr, k1 = 2 * pr + 1;
    float a = 0.0f, b = 0.0f;
    if (k0 < 308) a = (k0 < 52) ? wx[k0 * ZC + j] : wh[(k0 - 52) * ZC + j];
    if (k1 < 308) b = (k1 < 52) ? wx[k1 * ZC + j] : wh[(k1 - 52) * ZC + j];
    W2[idx] = __floats2half2_rn(a, b);
}

// conv1 3x3 (1->16) SAME + relu + maxpool2
__global__ __launch_bounds__(256) void conv1_pool(const float* __restrict__ in,
                                                  const float* __restrict__ w,
                                                  const float* __restrict__ bias,
                                                  float* __restrict__ out) {
    int idx = blockIdx.x * 256 + threadIdx.x;
    if (idx >= 256 * 32 * 32 * 16) return;
    int c = idx & 15, x = (idx >> 4) & 31, y = (idx >> 9) & 31, b = idx >> 14;
    const float* inb = in + (size_t)b * 4096;
    float bv = bias[c];
    float mx = 0.0f;
    #pragma unroll
    for (int dy = 0; dy < 2; ++dy)
    #pragma unroll
    for (int dx = 0; dx < 2; ++dx) {
        int oy = 2 * y + dy, ox = 2 * x + dx;
        float s = bv;
        #pragma unroll
        for (int ky = 0; ky < 3; ++ky) {
            int iy = oy + ky - 1;
            if (iy < 0 || iy > 63) continue;
            #pragma unroll
            for (int kx = 0; kx < 3; ++kx) {
                int ix = ox + kx - 1;
                if (ix < 0 || ix > 63) continue;
                s = fmaf(inb[iy * 64 + ix], w[(ky * 3 + kx) * 16 + c], s);
            }
        }
        mx = fmaxf(mx, fmaxf(s, 0.0f));
    }
    out[idx] = mx;
}

// conv2 3x3 (16->32) SAME + relu + maxpool2
__global__ __launch_bounds__(256) void conv2_pool(const float* __restrict__ p1,
                                                  const float* __restrict__ w,
                                                  const float* __restrict__ bias,
                                                  float* __restrict__ seq) {
    int idx = blockIdx.x * 256 + threadIdx.x;
    if (idx >= 256 * 16 * 16 * 32) return;
    int c = idx & 31, x = (idx >> 5) & 15, y = (idx >> 9) & 15, b = idx >> 13;
    const float* pb = p1 + (size_t)b * (32 * 32 * 16);
    float bv = bias[c];
    float mx = 0.0f;
    #pragma unroll
    for (int dy = 0; dy < 2; ++dy)
    #pragma unroll
    for (int dx = 0; dx < 2; ++dx) {
        int oy = 2 * y + dy, ox = 2 * x + dx;
        float s = bv;
        for (int ky = 0; ky < 3; ++ky) {
            int iy = oy + ky - 1;
            if (iy < 0 || iy > 31) continue;
            for (int kx = 0; kx < 3; ++kx) {
                int ix = ox + kx - 1;
                if (ix < 0 || ix > 31) continue;
                const float* pin = pb + (iy * 32 + ix) * 16;
                const float* pw  = w + (ky * 3 + kx) * 16 * 32 + c;
                #pragma unroll
                for (int ci2 = 0; ci2 < 16; ++ci2)
                    s = fmaf(pin[ci2], pw[ci2 * 32], s);
            }
        }
        mx = fmaxf(mx, fmaxf(s, 0.0f));
    }
    seq[idx] = mx;
}

// ---------------------------------------------------------------------------
// Persistent NTM scan. 128 blocks, 2 batch/block, 1024 threads (16 waves).
// ---------------------------------------------------------------------------
#define PSCLIP(b_, col_) fminf(fmaxf(pp[0][b_][col_] + pp[1][b_][col_] + pp[2][b_][col_] + pp[3][b_][col_] + hb[col_], -CLIPV), CLIPV)

__global__ __launch_bounds__(1024, 4) void ntm_scan2(
    const float* __restrict__ seq,     // [256][256][32]
    const __half2* __restrict__ W2,    // [NPR][1024] k-pair packed
    const float* __restrict__ lb,      // [1024]
    const float* __restrict__ hw,      // [256][92] (f32)
    const float* __restrict__ hb,      // [92]
    const float* __restrict__ ow,      // [276][8]
    const float* __restrict__ ob,      // [8]
    float* __restrict__ out8)          // [256][8]
{
    __shared__ float zpart[8][2][ZC];        // 64KB
    __shared__ float ci[2][KPAD];            // 0..31 xt, 32..51 reads, 52..307 h, pad 0
    __shared__ float Msh[2][MW][132];        // transposed memory [b][wi][n], pad 132
    __shared__ float wprev[2][2][NLOC];
    __shared__ float pp[4][2][PC];
    __shared__ float kvs[2][2][MW];
    __shared__ float evs[2][MW], avs[2][MW];
    __shared__ float rdp[8][2][MW];

    const int t = threadIdx.x;
    const int bs0 = blockIdx.x * 2;

    // ---- init state ----
    for (int i = t; i < 2 * KPAD; i += 1024) {
        int b = i / KPAD, k = i - b * KPAD;
        float v;
        if (k < 32)      v = seq[(size_t)(bs0 + b) * 8192 + k];
        else if (k < 52) v = 1e-6f;
        else             v = 0.0f;           // h and pad
        ci[b][k] = v;
    }
    for (int i = t; i < 2 * MW * 132; i += 1024) {
        int b = i / (MW * 132), r = i - b * (MW * 132);
        Msh[b][r / 132][r - (r / 132) * 132] = 1e-6f;
    }
    if (t < 512) {
        int b = t >> 8, r = t & 255;
        wprev[b][r >> 7][r & 127] = 1.0f / 128.0f;
    }
    float c_reg = 0.0f;    // cell state: thread t<512 owns (b=t>>8, u=t&255)
    __syncthreads();

    const int c  = t & 127;          // column base (cols c + 128*m)
    const int kq = t >> 7;           // 0..7 K-chunk
    const int k0 = kq * 40;
    const int pr0 = kq * 20;

    for (int step = 0; step < 256; ++step) {
        // ---- P1: z = ci @ [Wx;Wh], fp16 weights, 8 cols x 40-K per thread ----
        {
            float acc[8][2];
            #pragma unroll
            for (int m = 0; m < 8; ++m) { acc[m][0] = 0.0f; acc[m][1] = 0.0f; }
            const __half2* Wp = W2 + (size_t)pr0 * ZC + c;
            for (int p = 0; p < 20; p += 2) {
                float4 cA = *reinterpret_cast<const float4*>(&ci[0][k0 + 2 * p]);
                float4 cB = *reinterpret_cast<const float4*>(&ci[1][k0 + 2 * p]);
                #pragma unroll
                for (int m = 0; m < 8; ++m) {
                    float2 w0 = __half22float2(Wp[(size_t)p * ZC + m * 128]);
                    float2 w1 = __half22float2(Wp[(size_t)(p + 1) * ZC + m * 128]);
                    acc[m][0] = fmaf(w1.y, cA.w, fmaf(w1.x, cA.z, fmaf(w0.y, cA.y, fmaf(w0.x, cA.x, acc[m][0]))));
                    acc[m][1] = fmaf(w1.y, cB.w, fmaf(w1.x, cB.z, fmaf(w0.y, cB.y, fmaf(w0.x, cB.x, acc[m][1]))));
                }
            }
            #pragma unroll
            for (int m = 0; m < 8; ++m) {
                zpart[kq][0][c + 128 * m] = acc[m][0];
                zpart[kq][1][c + 128 * m] = acc[m][1];
            }
        }
        __syncthreads();   // B1

        // ---- P2: LSTM update; spare threads prefetch next xt ----
        if (t < 512) {
            int b = t >> 8, u = t & 255;
            float zi = lb[u], zf = lb[256 + u], zg = lb[512 + u], zo = lb[768 + u];
            #pragma unroll
            for (int q = 0; q < 8; ++q) {
                zi += zpart[q][b][u];       zf += zpart[q][b][256 + u];
                zg += zpart[q][b][512 + u]; zo += zpart[q][b][768 + u];
            }
            float cg = sigmoidf_(zf) * c_reg + sigmoidf_(zi) * tanhf(zg);
            c_reg = cg;
            ci[b][52 + u] = sigmoidf_(zo) * tanhf(cg);
        } else if (t < 576 && step < 255) {
            int q = t - 512, b = q >> 5, cc = q & 31;
            ci[b][cc] = seq[(size_t)(bs0 + b) * 8192 + (size_t)(step + 1) * 32 + cc];
        }
        __syncthreads();   // B2

        // ---- P3: head-param GEMM partials (4-way K split, f32 weights) ----
        if (t < 736) {
            int kq4 = t / 184, r = t - kq4 * 184, b = r / 92, col = r - b * 92;
            const float* hp = hw + (size_t)(kq4 * 64) * PC + col;
            const float* hs = &ci[b][52 + kq4 * 64];
            float s = 0.0f;
            #pragma unroll 8
            for (int u = 0; u < 64; ++u) s = fmaf(hs[u], hp[(size_t)u * PC], s);
            pp[kq4][b][col] = s;
        }
        __syncthreads();   // B3

        // ---- P4a: kv / erase / add vectors (inline ps reduce+clip) ----
        if (t < 80) {
            int b = t / 40, hh = (t / 20) & 1, wi = t % 20;
            kvs[b][hh][wi] = tanhf(PSCLIP(b, hh * 26 + wi));
        } else if (t >= 128 && t < 208) {
            int q = t - 128, b = q / 40, r2 = q % 40;
            if (r2 < 20) evs[b][r2]      = sigmoidf_(PSCLIP(b, 52 + r2));
            else         avs[b][r2 - 20] = tanhf(PSCLIP(b, 72 + (r2 - 20)));
        }
        __syncthreads();   // B4

        // ---- P4b: addressing, one wave per (b,hh); lane holds n=2l,2l+1 ----
        if (t < 256) {
            const int l = t & 63;
            const int b = t >> 7, hh = (t >> 6) & 1;
            const int hc = hh * 26;
            float beta  = softplusf_(PSCLIP(b, hc + 20));
            float g     = sigmoidf_(PSCLIP(b, hc + 21));
            float s0r = PSCLIP(b, hc + 22), s1r = PSCLIP(b, hc + 23), s2r = PSCLIP(b, hc + 24);
            float mS = fmaxf(s0r, fmaxf(s1r, s2r));
            float q0 = expf(s0r - mS), q1 = expf(s1r - mS), q2 = expf(s2r - mS);
            float qin = 1.0f / (q0 + q1 + q2);
            float sh0 = q0 * qin, sh1 = q1 * qin, sh2 = q2 * qin;
            float gamma = softplusf_(PSCLIP(b, hc + 25)) + 1.0f;

            float kvr[20]; float kn2 = 0.0f;
            #pragma unroll
            for (int wi = 0; wi < 20; ++wi) { kvr[wi] = kvs[b][hh][wi]; kn2 = fmaf(kvr[wi], kvr[wi], kn2); }
            float kden = sqrtf(kn2) + 1e-8f;

            float d0 = 0, d1 = 0, m20 = 0, m21 = 0;
            #pragma unroll
            for (int wi = 0; wi < 20; ++wi) {
                float2 mv = *reinterpret_cast<const float2*>(&Msh[b][wi][2 * l]);
                d0  = fmaf(kvr[wi], mv.x, d0);  d1  = fmaf(kvr[wi], mv.y, d1);
                m20 = fmaf(mv.x, mv.x, m20);    m21 = fmaf(mv.y, mv.y, m21);
            }
            float x0 = beta * (d0 / ((sqrtf(m20) + 1e-8f) * kden));
            float x1 = beta * (d1 / ((sqrtf(m21) + 1e-8f) * kden));
            // softmax over 128 locations (wave-local)
            float mx = fmaxf(x0, x1);
            #pragma unroll
            for (int o = 1; o < 64; o <<= 1) mx = fmaxf(mx, __shfl_xor(mx, o, 64));
            float e0 = expf(x0 - mx), e1 = expf(x1 - mx);
            float se = e0 + e1;
            #pragma unroll
            for (int o = 1; o < 64; o <<= 1) se += __shfl_xor(se, o, 64);
            float inv = 1.0f / se;
            // interpolate
            float2 wpv = *reinterpret_cast<const float2*>(&wprev[b][hh][2 * l]);
            float wg0 = g * (e0 * inv) + (1.0f - g) * wpv.x;
            float wg1 = g * (e1 * inv) + (1.0f - g) * wpv.y;
            // circular conv shift (s0 -> n+1, s1 -> n, s2 -> n-1)
            float wgm = __shfl(wg1, (l + 63) & 63, 64);
            float wgp = __shfl(wg0, (l + 1) & 63, 64);
            float wt0 = sh0 * wg1 + sh1 * wg0 + sh2 * wgm;
            float wt1 = sh0 * wgp + sh1 * wg1 + sh2 * wg0;
            // sharpen
            float wpw0 = expf(gamma * logf(wt0 + 1e-8f));
            float wpw1 = expf(gamma * logf(wt1 + 1e-8f));
            float ssum = wpw0 + wpw1;
            #pragma unroll
            for (int o = 1; o < 64; o <<= 1) ssum += __shfl_xor(ssum, o, 64);
            float rin = 1.0f / ssum;
            *reinterpret_cast<float2*>(&wprev[b][hh][2 * l]) = make_float2(wpw0 * rin, wpw1 * rin);
        }
        __syncthreads();   // B5

        // ---- P5p: read-vector partials (old M, new read weights) ----
        if (t < 320) {
            int nc = t / 40, r = t - nc * 40, b = r / 20, wi = r - b * 20;
            const int n0 = nc * 16;
            float s = 0.0f;
            #pragma unroll
            for (int n = n0; n < n0 + 16; ++n)
                s = fmaf(wprev[b][0][n], Msh[b][wi][n], s);
            rdp[nc][b][wi] = s;
        }
        __syncthreads();   // B6

        // ---- P5f: finish reads; P6: memory erase+add ----
        if (t < 40) {
            int b = t / 20, wi = t - b * 20;
            float s = 0.0f;
            #pragma unroll
            for (int nc = 0; nc < 8; ++nc) s += rdp[nc][b][wi];
            ci[b][32 + wi] = s;
        }
        for (int i = t; i < 2 * MW * NLOC; i += 1024) {
            int b = i / 2560, r = i - b * 2560, wi = r >> 7, n = r & 127;
            float wwn = wprev[b][1][n];
            Msh[b][wi][n] = Msh[b][wi][n] * (1.0f - wwn * evs[b][wi]) + wwn * avs[b][wi];
        }
        __syncthreads();   // B7
    }

    // ---- final NTM output head (h_255, reads_255) ----
    if (t < 16) {
        int b = t >> 3, o = t & 7;
        float s = ob[o];
        for (int u = 0; u < 256; ++u) s = fmaf(ci[b][52 + u], ow[u * 8 + o], s);
        #pragma unroll
        for (int wi = 0; wi < 20; ++wi) s = fmaf(ci[b][32 + wi], ow[(256 + wi) * 8 + o], s);
        out8[(bs0 + b) * 8 + o] = fminf(fmaxf(s, -CLIPV), CLIPV);
    }
}

// final dense [256,8]@[8,2] + softmax
__global__ __launch_bounds__(256) void final_dense(const float* __restrict__ out8,
                                                   const float* __restrict__ dw,
                                                   const float* __restrict__ db,
                                                   float* __restrict__ out) {
    int b = blockIdx.x * 256 + threadIdx.x;
    if (b >= 256) return;
    float l0 = db[0], l1 = db[1];
    #pragma unroll
    for (int k = 0; k < 8; ++k) {
        float v = out8[b * 8 + k];
        l0 = fmaf(v, dw[k * 2 + 0], l0);
        l1 = fmaf(v, dw[k * 2 + 1], l1);
    }
    float m = fmaxf(l0, l1);
    float q0 = expf(l0 - m), q1 = expf(l1 - m);
    float inv = 1.0f / (q0 + q1);
    out[b * 2 + 0] = q0 * inv;
    out[b * 2 + 1] = q1 * inv;
}

extern "C" void kernel_launch(void* const* d_in, const int* in_sizes, int n_in,
                              void* d_out, int out_size, void* d_ws, size_t ws_size,
                              hipStream_t stream) {
    const float* inputs = (const float*)d_in[0];
    const float* c1w = (const float*)d_in[1];
    const float* c1b = (const float*)d_in[2];
    const float* c2w = (const float*)d_in[3];
    const float* c2b = (const float*)d_in[4];
    const float* lwx = (const float*)d_in[5];
    const float* lwh = (const float*)d_in[6];
    const float* lb  = (const float*)d_in[7];
    const float* hw  = (const float*)d_in[8];
    const float* hb  = (const float*)d_in[9];
    const float* ow  = (const float*)d_in[10];
    const float* ob  = (const float*)d_in[11];
    const float* dw  = (const float*)d_in[12];
    const float* db  = (const float*)d_in[13];
    float* out = (float*)d_out;

    float* ws   = (float*)d_ws;
    float* p1   = ws;                   // 256*32*32*16 = 4,194,304 floats
    float* seq  = ws + 4194304;         // 256*256*32   = 2,097,152 floats
    float* W2f  = ws + 6291456;         // NPR*1024 u32 =   163,840 "floats"
    float* out8 = ws + 6455296;         // 256*8
    __half2* W2 = (__half2*)W2f;

    hipLaunchKernelGGL(prep_W2,     dim3(640),   dim3(256),  0, stream, lwx, lwh, W2);
    hipLaunchKernelGGL(conv1_pool,  dim3(16384), dim3(256),  0, stream, inputs, c1w, c1b, p1);
    hipLaunchKernelGGL(conv2_pool,  dim3(8192),  dim3(256),  0, stream, p1, c2w, c2b, seq);
    hipLaunchKernelGGL(ntm_scan2,   dim3(128),   dim3(1024), 0, stream, seq, W2, lb, hw, hb, ow, ob, out8);
    hipLaunchKernelGGL(final_dense, dim3(1),     dim3(256),  0, stream, out8, dw, db, out);
}